// Round 5
// baseline (22.457 us; speedup 1.0000x reference)
//
#include <hip/hip_runtime.h>
#include <hip/hip_fp16.h>

#define NB 16384     // batch rows
#define ND 256       // d_in (GEMM K)
#define NH 1024      // hidden (GEMM N)
#define NK 16        // sparse fan-in

using f16x8 = __attribute__((ext_vector_type(8))) _Float16;
using f32x4 = __attribute__((ext_vector_type(4))) float;

__device__ __forceinline__ float fast_tanh(float x) {
    // tanh(x) = 1 - 2/(exp(2x)+1); saturates correctly at +-inf
    float e = __expf(2.0f * x);
    return 1.0f - 2.0f * __builtin_amdgcn_rcpf(e + 1.0f);
}

__device__ __forceinline__ void scat8(float (&a)[8], int ii, float ww, int d0) {
#pragma unroll
    for (int e = 0; e < 8; ++e)
        if (ii == d0 + e) a[e] += ww;   // static index, predicated add
}

// ---------------------------------------------------------------------------
// Kernel 1: scatter w1 into FRAGMENT-ORDERED dense Wf (f16), vectorized.
// Fragment block (c, ks): 16-col chunk c, k-slice ks (k = 32ks..32ks+31).
// MFMA lane l = kg*16+ml holds W[col=16c+ml][k=32ks+8kg .. +8].
// Flat: Wf[((c*8+ks)*64 + l)*8 + e] -> each B-fragment load is one contiguous
// 1KB block (lane*16B), perfectly coalesced.
// ---------------------------------------------------------------------------
__global__ __launch_bounds__(128) void build_w_kernel(
        const int* __restrict__ idx, const float* __restrict__ w1,
        _Float16* __restrict__ Wf) {
    int t = blockIdx.x * 128 + threadIdx.x;      // NH*32 = 32768 threads
    int h = t >> 5;
    int g = t & 31;
    int d0 = g << 3;
    const int4*   ip = reinterpret_cast<const int4*>(idx + h * NK);
    const float4* wp = reinterpret_cast<const float4*>(w1 + h * NK);
    float a[8];
#pragma unroll
    for (int e = 0; e < 8; ++e) a[e] = 0.f;
#pragma unroll
    for (int j = 0; j < 4; ++j) {
        int4   I = ip[j];
        float4 V = wp[j];
        scat8(a, I.x, V.x, d0);
        scat8(a, I.y, V.y, d0);
        scat8(a, I.z, V.z, d0);
        scat8(a, I.w, V.w, d0);
    }
    int c  = h >> 4;
    int ml = h & 15;
    int ks = g >> 2;
    int kg = g & 3;
    size_t off = (((size_t)(c * 8 + ks)) * 64 + kg * 16 + ml) * 8;
    f16x8 o;
#pragma unroll
    for (int e = 0; e < 8; ++e) o[e] = (_Float16)a[e];
    *reinterpret_cast<f16x8*>(&Wf[off]) = o;
}

// ---------------------------------------------------------------------------
// Kernel 2: fully-fused. Block = 64 rows x ALL 1024 cols; 8 waves, wave w
// owns cols [w*128, w*128+128) = 8 chunks of 16, visited in ROTATED order
// start = ((bx>>3)+w)&7 (spreads the chip-wide Wf read burst across L2 and
// desyncs co-SIMD waves' waitcnt points). A held in registers (af[4][8])
// after one swizzled-LDS stage of x. B streamed from fragment-ordered Wf
// (L2-resident) with half-chunk ping-pong prefetch. b1/w2 loads issued at
// the TOP of each iteration so the epilogue wait is vmcnt(8), never a
// pipeline drain. Epilogue: tanh(acc+b1)*w2 into row partials; final shfl +
// LDS reduce, tanh, store. No atomics, barrier-free main loop.
// ---------------------------------------------------------------------------
__global__ __launch_bounds__(512, 2) void fused_kernel(
        const float* __restrict__ x, const _Float16* __restrict__ Wf,
        const float* __restrict__ b1, const float* __restrict__ w2,
        const float* __restrict__ b2, float* __restrict__ out) {
    __shared__ _Float16 lA[64 * 256];   // 32 KB, 16B chunks swizzled: c ^= (r&7)
    __shared__ float red[8 * 64];       // 2 KB cross-wave reduction

    const int t = threadIdx.x;
    const int lane = t & 63;
    const int w = t >> 6;               // wave 0..7
    const int gm0 = blockIdx.x * 64;
    const int ml = lane & 15;
    const int kg = lane >> 4;
    const int start = ((blockIdx.x >> 3) + w) & 7;   // chunk rotation

    // ---- issue x loads first (HBM), then start-chunk B loads (L2) ----
    const int sr  = t >> 3;             // 0..63 staging row
    const int sub = t & 7;              // 32 f32 each
    const float4* xsrc = reinterpret_cast<const float4*>(
        x + (size_t)(gm0 + sr) * ND + sub * 32);
    float4 v[8];
#pragma unroll
    for (int j = 0; j < 8; ++j) v[j] = xsrc[j];

    const _Float16* gW = Wf + (size_t)w * 32768 + (size_t)lane * 8;
    f16x8 bA[4], bB[4];
    {
        const _Float16* p0 = gW + start * 4096;
#pragma unroll
        for (int ks = 0; ks < 4; ++ks)
            bA[ks] = *reinterpret_cast<const f16x8*>(p0 + ks * 512);
#pragma unroll
        for (int ks = 0; ks < 4; ++ks)
            bB[ks] = *reinterpret_cast<const f16x8*>(p0 + 2048 + ks * 512);
    }

    // ---- stage x tile (64x256) -> LDS f16, swizzled ----
#pragma unroll
    for (int q = 0; q < 4; ++q) {
        int c = sub * 4 + q;            // 16B chunk index 0..31
        f16x8 hh;
        hh[0] = (_Float16)v[2*q].x;   hh[1] = (_Float16)v[2*q].y;
        hh[2] = (_Float16)v[2*q].z;   hh[3] = (_Float16)v[2*q].w;
        hh[4] = (_Float16)v[2*q+1].x; hh[5] = (_Float16)v[2*q+1].y;
        hh[6] = (_Float16)v[2*q+1].z; hh[7] = (_Float16)v[2*q+1].w;
        int a16 = sr * 32 + (c ^ (sr & 7));
        *reinterpret_cast<f16x8*>(&lA[a16 * 8]) = hh;
    }
    __syncthreads();

    // ---- pull this wave's A fragments into registers (whole kernel) ----
    f16x8 af[4][8];                     // [mi][ks]
#pragma unroll
    for (int mi = 0; mi < 4; ++mi)
#pragma unroll
        for (int ks = 0; ks < 8; ++ks) {
            int r = mi * 16 + ml;
            int c = ks * 4 + kg;
            af[mi][ks] = *reinterpret_cast<const f16x8*>(
                &lA[(r * 32 + (c ^ (r & 7))) * 8]);
        }

    float rowpart[4][4];
#pragma unroll
    for (int mi = 0; mi < 4; ++mi)
#pragma unroll
        for (int r4 = 0; r4 < 4; ++r4) rowpart[mi][r4] = 0.f;

    // ---- main loop: runtime loop over 8 rotated chunks ----
#pragma unroll 1
    for (int nc = 0; nc < 8; ++nc) {
        const int ncc = (start + nc) & 7;
        // issue b1/w2 FIRST: oldest in vmcnt queue -> epilogue wait leaves
        // the B prefetches in flight
        float b1v = b1[w * 128 + ncc * 16 + ml];
        float w2v = w2[w * 128 + ncc * 16 + ml];

        f32x4 acc[4];
#pragma unroll
        for (int mi = 0; mi < 4; ++mi) acc[mi] = f32x4{0.f, 0.f, 0.f, 0.f};

        const int ncn = (start + nc + 1) & 7;
        const _Float16* pn = gW + ncn * 4096;

        // compute first half (bA), then prefetch next chunk's first half
        __builtin_amdgcn_s_setprio(1);
#pragma unroll
        for (int ks = 0; ks < 4; ++ks)
#pragma unroll
            for (int mi = 0; mi < 4; ++mi)
                acc[mi] = __builtin_amdgcn_mfma_f32_16x16x32_f16(
                    af[mi][ks], bA[ks], acc[mi], 0, 0, 0);
        __builtin_amdgcn_s_setprio(0);
        if (nc != 7) {
#pragma unroll
            for (int ks = 0; ks < 4; ++ks)
                bA[ks] = *reinterpret_cast<const f16x8*>(pn + ks * 512);
        }

        // compute second half (bB), then prefetch next chunk's second half
        __builtin_amdgcn_s_setprio(1);
#pragma unroll
        for (int ks = 0; ks < 4; ++ks)
#pragma unroll
            for (int mi = 0; mi < 4; ++mi)
                acc[mi] = __builtin_amdgcn_mfma_f32_16x16x32_f16(
                    af[mi][4 + ks], bB[ks], acc[mi], 0, 0, 0);
        __builtin_amdgcn_s_setprio(0);
        if (nc != 7) {
#pragma unroll
            for (int ks = 0; ks < 4; ++ks)
                bB[ks] = *reinterpret_cast<const f16x8*>(pn + 2048 + ks * 512);
        }

        // epilogue: tanh(pre+b1)*w2 into row partials (waits only b1v/w2v)
#pragma unroll
        for (int mi = 0; mi < 4; ++mi)
#pragma unroll
            for (int r4 = 0; r4 < 4; ++r4)
                rowpart[mi][r4] += fast_tanh(acc[mi][r4] + b1v) * w2v;
    }

    // ---- reduce over the 16 col-lanes of each group ----
#pragma unroll
    for (int mi = 0; mi < 4; ++mi)
#pragma unroll
        for (int r4 = 0; r4 < 4; ++r4) {
            float vv = rowpart[mi][r4];
            vv += __shfl_xor(vv, 1);
            vv += __shfl_xor(vv, 2);
            vv += __shfl_xor(vv, 4);
            vv += __shfl_xor(vv, 8);
            rowpart[mi][r4] = vv;
        }
    if (ml == 0) {
#pragma unroll
        for (int mi = 0; mi < 4; ++mi)
#pragma unroll
            for (int r4 = 0; r4 < 4; ++r4)
                red[w * 64 + mi * 16 + kg * 4 + r4] = rowpart[mi][r4];
    }
    __syncthreads();

    // ---- cross-wave sum + final tanh + store ----
    if (t < 64) {
        float s = 0.f;
#pragma unroll
        for (int j = 0; j < 8; ++j) s += red[j * 64 + t];
        out[gm0 + t] = fast_tanh(s + b2[0]);
    }
}

extern "C" void kernel_launch(void* const* d_in, const int* in_sizes, int n_in,
                              void* d_out, int out_size, void* d_ws, size_t ws_size,
                              hipStream_t stream) {
    const float* x   = (const float*)d_in[0];
    const int*   idx = (const int*)d_in[1];
    const float* w1  = (const float*)d_in[2];
    const float* b1  = (const float*)d_in[3];
    const float* w2  = (const float*)d_in[4];
    const float* b2  = (const float*)d_in[5];
    float* out = (float*)d_out;

    _Float16* Wf = (_Float16*)d_ws;     // 512 KB fragment-ordered W

    build_w_kernel<<<(NH * 32) / 128, 128, 0, stream>>>(idx, w1, Wf);
    fused_kernel<<<NB / 64, 512, 0, stream>>>(x, Wf, b1, w2, b2, out);
}